// Round 1
// baseline (299.311 us; speedup 1.0000x reference)
//
#include <hip/hip_runtime.h>

// conv1d: out[b,i] = sum_{k<16,d<512} x[b,i+k,d] * w[k,d] + bias, zero-pad at end.
// Memory-bound (256 MiB input, ~43 us HBM floor). One wave = 16 consecutive
// outputs; lane owns an 8-float d-slice; filter fully in registers (128 VGPR).

namespace {
constexpr int S = 4096;
constexpr int D = 512;
constexpr int K = 16;
constexpr int R = 16;              // outputs per wave
constexpr int FRAMES = R + K - 1;  // 31 frames per strip (incl. halo)
constexpr int STRIPS = S / R;      // 256 strips per batch row
constexpr int B = 32;

__global__ __launch_bounds__(256, 2)
void conv1d_kernel(const float* __restrict__ x,
                   const float* __restrict__ filt,
                   const float* __restrict__ bias,
                   float* __restrict__ out) {
  const int lane = threadIdx.x & 63;
  const int wv = blockIdx.x * 4 + (threadIdx.x >> 6);  // global wave id
  const int b = wv >> 8;               // wv / STRIPS
  const int strip = wv & (STRIPS - 1); // consecutive waves -> consecutive strips (L2/LLC halo reuse)
  const int i0 = strip * R;

  const float bias0 = bias[0];

  // lane's d-slice base: coalesced across lanes (2 KB per frame per wave)
  const float* xp = x + ((size_t)b * S + i0) * D + lane * 8;

  // filter in registers: w[k][lane*8 .. lane*8+8). filt index = k*D + d.
  float4 w0[K], w1[K];
#pragma unroll
  for (int k = 0; k < K; ++k) {
    const float* wp = filt + k * D + lane * 8;
    w0[k] = *reinterpret_cast<const float4*>(wp);
    w1[k] = *reinterpret_cast<const float4*>(wp + 4);
  }

  float acc[R];
#pragma unroll
  for (int o = 0; o < R; ++o) acc[o] = 0.f;

  // frames beyond S are the reference's zero padding: skip them
  const int nvalid = (S - i0 < FRAMES) ? (S - i0) : FRAMES;

#pragma unroll
  for (int tt = 0; tt < FRAMES; ++tt) {
    if (tt < nvalid) {  // wave-uniform branch
      const float* fp = xp + tt * D;
      const float4 xa = *reinterpret_cast<const float4*>(fp);
      const float4 xb = *reinterpret_cast<const float4*>(fp + 4);
      // frame tt contributes to outputs o = tt-k for k in [klo, khi] (compile-time)
      const int klo = (tt - (R - 1) > 0) ? (tt - (R - 1)) : 0;
      const int khi = (tt < (K - 1)) ? tt : (K - 1);
#pragma unroll
      for (int k = klo; k <= khi; ++k) {
        float s = acc[tt - k];  // compile-time index after unroll
        s = fmaf(xa.x, w0[k].x, s);
        s = fmaf(xa.y, w0[k].y, s);
        s = fmaf(xa.z, w0[k].z, s);
        s = fmaf(xa.w, w0[k].w, s);
        s = fmaf(xb.x, w1[k].x, s);
        s = fmaf(xb.y, w1[k].y, s);
        s = fmaf(xb.z, w1[k].z, s);
        s = fmaf(xb.w, w1[k].w, s);
        acc[tt - k] = s;
      }
    }
  }

  // 16 independent 64-lane butterfly reductions (d-slice partials -> scalar)
  float stval = 0.f;
#pragma unroll
  for (int o = 0; o < R; ++o) {
    float s = acc[o];
#pragma unroll
    for (int m = 1; m < 64; m <<= 1) s += __shfl_xor(s, m, 64);
    if (lane == o) stval = s;
  }

  if (lane < R) out[(size_t)b * S + i0 + lane] = stval + bias0;
}
}  // namespace

extern "C" void kernel_launch(void* const* d_in, const int* in_sizes, int n_in,
                              void* d_out, int out_size, void* d_ws, size_t ws_size,
                              hipStream_t stream) {
  const float* x = (const float*)d_in[0];
  const float* filt = (const float*)d_in[1];
  const float* bias = (const float*)d_in[2];
  float* out = (float*)d_out;

  const int waves = B * STRIPS;   // 8192 waves
  const int blocks = waves / 4;   // 256 threads = 4 waves per block
  hipLaunchKernelGGL(conv1d_kernel, dim3(blocks), dim3(256), 0, stream,
                     x, filt, bias, out);
}